// Round 8
// baseline (693.361 us; speedup 1.0000x reference)
//
#include <hip/hip_runtime.h>
#include <hip/hip_cooperative_groups.h>
#include <math.h>

namespace cg = cooperative_groups;

#define TT 2048
#define BBATCH 256
#define DDIM 57
#define NROWS (BBATCH*TT)
#define NF 524288.0f
#define U 8
#define G 4              // slots per barrier epoch
#define NBUF 8           // 2*G h-buffers (producer epoch e, consumer e+1)
#define XROWS 64         // rows per xg0 block

#define K1 (-1.4426950408889634f)   // -log2(e)   : sigmoid rows (i,f,o)
#define K2 (-2.8853900817779268f)   // -2 log2(e) : tanh rows (g) and tanh(c)

__device__ __forceinline__ float bcastl(float v, int k) {
  return __uint_as_float((unsigned)__builtin_amdgcn_readlane((int)__float_as_uint(v), k));
}
__device__ __forceinline__ float rcpf(float x) { return __builtin_amdgcn_rcpf(x); }
__device__ __forceinline__ float exp2f_(float x) { return __builtin_amdgcn_exp2f(x); }

// quad_perm broadcast: all 4 lanes of each quad get lane (PAT&3)'s value.
template<int PAT>
__device__ __forceinline__ float quadb(float v) {
  return __int_as_float(__builtin_amdgcn_update_dpp(0, __float_as_int(v), PAT, 0xF, 0xF, true));
}

// R14 xg0 (unchanged): LDS-staged tile GEMM, 64 rows/block, uniform
// ds_read_b128 broadcasts, high occupancy so DS/VALU latency is TLP-hidden.
__global__ __launch_bounds__(256) void xg0_gemm_k(
    const float* __restrict__ x, const float* __restrict__ Wih,
    const float* __restrict__ bih, const float* __restrict__ bhh,
    float* __restrict__ xg0)
{
  const int tid = threadIdx.x;
  const int l   = tid & 63;          // output lane (scan layout)
  const int w   = tid >> 6;          // wave id: rows w*16 .. w*16+15
  const int g   = (l & 3) * 16 + (l >> 2);
  const float fac = ((l & 3) == 2) ? K2 : K1;

  __shared__ __align__(16) float xs[XROWS][60];

  float wv[60];
  #pragma unroll
  for (int d = 0; d < 60; ++d) wv[d] = (d < DDIM) ? fac * Wih[g*DDIM + d] : 0.f;
  const float bias = fac * (bih[g] + bhh[g]);

  const int rbase = blockIdx.x * XROWS;
  const float4* xsrc = (const float4*)(x + (size_t)rbase * DDIM); // 64*57*4 % 16 == 0: aligned
  #pragma unroll
  for (int it = 0; it < 4; ++it) {
    int i = tid + it*256;
    if (i < 912) {                     // 912 float4 = 3648 floats = 64 rows
      float4 v = xsrc[i];
      int f0 = 4*i;
      int r0 = f0/57, d0 = f0 - r0*57;            xs[r0][d0] = v.x;
      int f1 = f0+1, r1 = f1/57, d1 = f1 - r1*57; xs[r1][d1] = v.y;
      int f2 = f0+2, r2 = f2/57, d2 = f2 - r2*57; xs[r2][d2] = v.z;
      int f3 = f0+3, r3 = f3/57, d3 = f3 - r3*57; xs[r3][d3] = v.w;
    }
  }
  if (tid < 192) {                     // zero pad cols 57..59 (avoid NaN*0)
    int r = tid/3, c = 57 + (tid - 3*r);
    xs[r][c] = 0.f;
  }
  __syncthreads();

  #pragma unroll
  for (int rr = 0; rr < 16; ++rr) {
    const int r = w*16 + rr;           // wave-uniform -> ds_read broadcast
    const float4* xr = (const float4*)&xs[r][0];
    float a0 = bias, a1 = 0.f, a2 = 0.f, a3 = 0.f;
    #pragma unroll
    for (int i = 0; i < 15; ++i) {
      float4 v = xr[i];
      a0 += wv[4*i]   * v.x;
      a1 += wv[4*i+1] * v.y;
      a2 += wv[4*i+2] * v.z;
      a3 += wv[4*i+3] * v.w;
    }
    xg0[(size_t)(rbase + r)*64 + l] = (a0 + a1) + (a2 + a3);
  }
}

// R15: cooperative fused scan. R14's 3-wave epoch-barrier scan body is
// unchanged, but (1) h2 lives in LDS (128KB/block, total 140KB <= 160KB,
// occupancy was already 1 block/CU) - kills the 32MB h2 write + 32MB read;
// (2) after the scan, partials -> grid.sync() -> EVERY block redundantly
// reduces the 8K partials (32KB, L2-resident) -> coef -> transforms its own
// LDS h2 -> writes out directly. Rows t>=len are analytically the coef bias
// (h=0 through BN+FC), so no zero-fill. prep_k and finalize_k deleted:
// 2 launches total (gap accounting showed ~40us/kernel-boundary in the
// timed region across R1-R7).
__global__ __launch_bounds__(192, 1) void lstm_scan_fused_k(
    const float* __restrict__ xg0,
    const int*   __restrict__ lengths,
    const float* __restrict__ Whh0,
    const float* __restrict__ Wih1, const float* __restrict__ Whh1,
    const float* __restrict__ bih1, const float* __restrict__ bhh1,
    const float* __restrict__ Wih2, const float* __restrict__ Whh2,
    const float* __restrict__ bih2, const float* __restrict__ bhh2,
    const float* __restrict__ gamma, const float* __restrict__ beta,
    const float* __restrict__ fcw, const float* __restrict__ fcb,
    float* __restrict__ out, float* __restrict__ partial)
{
  const int tid  = threadIdx.x;
  const int wave = tid >> 6;
  const int lane = tid & 63;
  const int gt   = lane & 3;       // 0=i 1=f 2=g 3=o
  const int ch   = lane >> 2;      // channel 0..15
  const int g    = gt*16 + ch;     // weight row (PyTorch i,f,g,o blocks)
  const int b    = blockIdx.x;
  const int len  = lengths[b];
  const bool isg = (gt == 2);
  const float fac = isg ? K2 : K1;
  const float mg = isg ? (2.f*K2) : 1.f;   // g-gate act = K2*tanh (pre-scaled)
  const float ag = isg ? (-K2)    : 0.f;

  __shared__ float lds_h0[NBUF][U][16];
  __shared__ float lds_h1[NBUF][U][16];
  __shared__ __align__(16) float lds_h2[TT][16];   // layer-2 h, never global
  __shared__ float red[6][32];
  __shared__ float coef_s[68];

  float wa[16], wb[16];
  float bias = 0.f;
  if (wave == 0) {
    #pragma unroll
    for (int k = 0; k < 16; ++k) { wb[k] = fac * Whh0[g*16 + k]; wa[k] = 0.f; }
  } else if (wave == 1) {
    #pragma unroll
    for (int k = 0; k < 16; ++k) { wa[k] = fac * Wih1[g*16 + k]; wb[k] = fac * Whh1[g*16 + k]; }
    bias = fac * (bih1[g] + bhh1[g]);
  } else {
    #pragma unroll
    for (int k = 0; k < 16; ++k) { wa[k] = fac * Wih2[g*16 + k]; wb[k] = fac * Whh2[g*16 + k]; }
    bias = fac * (bih2[g] + bhh2[g]);
  }

  float hs = 0.f, csK = 0.f;            // csK = K2 * c  (pre-scaled recurrence)
  float sum = 0.f, sq = 0.f;
  const int base = b*TT*64 + lane;

  auto lstm_update = [&](float dot) {
    float s   = rcpf(1.f + exp2f_(dot));
    float act = fmaf(s, mg, ag);          // sigmoid, or K2*tanh for g-gate
    float gi = quadb<0x00>(act);
    float gf = quadb<0x55>(act);
    float gg = quadb<0xAA>(act);          // = K2*tanh(g)
    float go = quadb<0xFF>(act);
    float go2 = go + go;                  // off critical path
    csK = fmaf(gf, csK, gg * gi);         // K2*(f*c + i*g)
    float r = rcpf(1.f + exp2f_(csK));
    hs = fmaf(go2, r, -go);               // go * tanh(c)
  };
  auto owndot = [&](float seed) {         // seed + Whh' . h_own
    float hb[16];                         // ALL broadcasts first (R8 lesson)
    #pragma unroll
    for (int k = 0; k < 16; ++k) hb[k] = bcastl(hs, 4*k);
    float a0 = seed, a1 = 0.f, a2 = 0.f, a3 = 0.f;
    #pragma unroll
    for (int k = 0; k < 16; k += 4) {
      a0 += wb[k]   * hb[k];
      a1 += wb[k+1] * hb[k+1];
      a2 += wb[k+2] * hb[k+2];
      a3 += wb[k+3] * hb[k+3];
    }
    return (a0 + a1) + (a2 + a3);
  };
  auto indot = [&](const float* hin) {    // bias + Wih' . hin (register vector)
    float a0 = bias, a1 = 0.f, a2 = 0.f, a3 = 0.f;
    #pragma unroll
    for (int k = 0; k < 16; k += 4) {
      a0 += wa[k]   * hin[k];
      a1 += wa[k+1] * hin[k+1];
      a2 += wa[k+2] * hin[k+2];
      a3 += wa[k+3] * hin[k+3];
    }
    return (a0 + a1) + (a2 + a3);
  };

  const int NS = (len + U - 1) / U;
  const int E  = (NS + 2*G - 1) / G + 1;

  float cur[U], nxt[U];
  if (wave == 0) {
    #pragma unroll
    for (int j = 0; j < U; ++j) cur[j] = xg0[base + j*64];
    #pragma unroll
    for (int j = 0; j < U; ++j) {
      int ip = U + j; ip = ip > TT-1 ? TT-1 : ip;
      nxt[j] = xg0[base + ip*64];
    }
  }

  for (int e = 0; e < E; ++e) {
    #pragma unroll 1
    for (int q = 0; q < G; ++q) {
      const int tw = G*e + q;
      if (wave == 0) {
        const int t = tw;
        if (t < NS) {
          const int p = t & (NBUF-1);
          float ld[U];
          #pragma unroll
          for (int j = 0; j < U; ++j) {
            int ip = (t + 2)*U + j; ip = ip > TT-1 ? TT-1 : ip;
            ld[j] = xg0[base + ip*64];
          }
          #pragma unroll
          for (int j = 0; j < U; ++j) {
            lstm_update(owndot(cur[j]));
            if (gt == 0) lds_h0[p][j][ch] = hs;
          }
          #pragma unroll
          for (int j = 0; j < U; ++j) { cur[j] = nxt[j]; nxt[j] = ld[j]; }
        }
      } else if (wave == 1) {
        const int t = tw - G;
        if (t >= 0 && t < NS) {
          const int p = t & (NBUF-1);
          float xin[U];
          #pragma unroll
          for (int j = 0; j < U; ++j) {   // ALL input-dots up front, off-chain
            const float4* hp = (const float4*)&lds_h0[p][j][0];
            float4 h0v = hp[0], h1v = hp[1], h2v = hp[2], h3v = hp[3];
            float hin[16] = {h0v.x,h0v.y,h0v.z,h0v.w, h1v.x,h1v.y,h1v.z,h1v.w,
                             h2v.x,h2v.y,h2v.z,h2v.w, h3v.x,h3v.y,h3v.z,h3v.w};
            xin[j] = indot(hin);
          }
          #pragma unroll
          for (int j = 0; j < U; ++j) {
            lstm_update(owndot(xin[j]));
            if (gt == 0) lds_h1[p][j][ch] = hs;
          }
        }
      } else {
        const int t = tw - 2*G;
        if (t >= 0 && t < NS) {
          const int p = t & (NBUF-1);
          float xin[U];
          #pragma unroll
          for (int j = 0; j < U; ++j) {
            const float4* hp = (const float4*)&lds_h1[p][j][0];
            float4 h0v = hp[0], h1v = hp[1], h2v = hp[2], h3v = hp[3];
            float hin[16] = {h0v.x,h0v.y,h0v.z,h0v.w, h1v.x,h1v.y,h1v.z,h1v.w,
                             h2v.x,h2v.y,h2v.z,h2v.w, h3v.x,h3v.y,h3v.z,h3v.w};
            xin[j] = indot(hin);
          }
          #pragma unroll
          for (int j = 0; j < U; ++j) {
            lstm_update(owndot(xin[j]));
            const int ts = t*U + j;
            if (ts < len) {
              if (gt == 0) lds_h2[ts][ch] = hs;
              sum += hs; sq += hs*hs;
            }
          }
        }
      }
    }
    __syncthreads();
  }

  // ---- epilogue: BN stats + FC, all in this kernel ----
  if (wave == 2 && gt == 0) {            // non-atomic per-block partials
    partial[b*32 + ch]      = sum;
    partial[b*32 + 16 + ch] = sq;
    __threadfence();                     // visible before grid sync
  }
  cg::this_grid().sync();

  // Redundant per-block reduction of all 8192 partials (32KB, L2-hit).
  const int c = tid & 31, chunk = tid >> 5;   // 6 chunks x 32 channels = 192
  float acc = 0.f;
  for (int bb = chunk; bb < BBATCH; bb += 6)
    acc += partial[bb*32 + c];
  red[chunk][c] = acc;
  __syncthreads();
  if (tid < 32) {
    float tot = 0.f;
    #pragma unroll
    for (int k = 0; k < 6; ++k) tot += red[k][tid];
    red[0][tid] = tot;
  }
  __syncthreads();
  if (tid < 64) {
    const int o = tid >> 4, c2 = tid & 15;
    const float inv_n = 1.0f / NF;
    float mean = red[0][c2] * inv_n;
    float var  = red[0][16 + c2] * inv_n - mean*mean;
    float sc = gamma[c2] * rsqrtf(var + 1e-5f);
    float tb = beta[c2] - mean * sc;
    float woc = fcw[o*16 + c2];
    coef_s[tid] = sc * woc;
    float term = tb * woc;
    #pragma unroll
    for (int off = 1; off < 16; off <<= 1) term += __shfl_xor(term, off, 16);
    if (c2 == 0) coef_s[64 + o] = fcb[o] + term;
  }
  __syncthreads();

  // Transform own h2 rows from LDS -> out. t >= len rows are the bias vector
  // (h=0 through BN+FC), no h2 read needed.
  float4* outp = (float4*)out + (size_t)b*TT;
  const float4 bias4 = make_float4(coef_s[64], coef_s[65], coef_s[66], coef_s[67]);
  for (int t = tid; t < TT; t += 192) {
    float4 o4;
    if (t < len) {
      const float4* hp = (const float4*)&lds_h2[t][0];
      float4 v0 = hp[0], v1 = hp[1], v2 = hp[2], v3 = hp[3];
      float hv[16] = {v0.x,v0.y,v0.z,v0.w, v1.x,v1.y,v1.z,v1.w,
                      v2.x,v2.y,v2.z,v2.w, v3.x,v3.y,v3.z,v3.w};
      float* op = &o4.x;
      #pragma unroll
      for (int o = 0; o < 4; ++o) {
        float a = coef_s[64 + o];
        #pragma unroll
        for (int c3 = 0; c3 < 16; ++c3) a += coef_s[o*16 + c3] * hv[c3];
        op[o] = a;
      }
    } else {
      o4 = bias4;
    }
    outp[t] = o4;
  }
}

extern "C" void kernel_launch(void* const* d_in, const int* in_sizes, int n_in,
                              void* d_out, int out_size, void* d_ws, size_t ws_size,
                              hipStream_t stream)
{
  const float* x     = (const float*)d_in[0];
  const int* lengths = (const int*)d_in[1];
  const float* W_ih0 = (const float*)d_in[2];
  const float* W_hh0 = (const float*)d_in[3];
  const float* b_ih0 = (const float*)d_in[4];
  const float* b_hh0 = (const float*)d_in[5];
  const float* W_ih1 = (const float*)d_in[6];
  const float* W_hh1 = (const float*)d_in[7];
  const float* b_ih1 = (const float*)d_in[8];
  const float* b_hh1 = (const float*)d_in[9];
  const float* W_ih2 = (const float*)d_in[10];
  const float* W_hh2 = (const float*)d_in[11];
  const float* b_ih2 = (const float*)d_in[12];
  const float* b_hh2 = (const float*)d_in[13];
  const float* gamma = (const float*)d_in[14];
  const float* beta  = (const float*)d_in[15];
  const float* fcw   = (const float*)d_in[16];
  const float* fcb   = (const float*)d_in[17];
  float* out = (float*)d_out;

  float* ws      = (float*)d_ws;
  float* xg0     = ws;                        // B*T*64 floats (128 MB)
  float* partial = ws + 33554432;             // 256*32 floats

  hipLaunchKernelGGL(xg0_gemm_k, dim3(NROWS/XROWS), dim3(256), 0, stream,
                     x, W_ih0, b_ih0, b_hh0, xg0);

  void* kargs[] = {
    (void*)&xg0, (void*)&lengths, (void*)&W_hh0,
    (void*)&W_ih1, (void*)&W_hh1, (void*)&b_ih1, (void*)&b_hh1,
    (void*)&W_ih2, (void*)&W_hh2, (void*)&b_ih2, (void*)&b_hh2,
    (void*)&gamma, (void*)&beta, (void*)&fcw, (void*)&fcb,
    (void*)&out, (void*)&partial
  };
  hipLaunchCooperativeKernel((void*)lstm_scan_fused_k, dim3(BBATCH), dim3(192),
                             kargs, 0, stream);
}

// Round 9
// 646.068 us; speedup vs baseline: 1.0732x; 1.0732x over previous
//
#include <hip/hip_runtime.h>
#include <math.h>

#define TT 2048
#define BBATCH 256
#define DDIM 57
#define NROWS (BBATCH*TT)
#define NF 524288.0f
#define U 8
#define G 4              // slots per barrier epoch
#define NBUF 8           // 2*G h-buffers (producer epoch e, consumer e+1)
#define XROWS 64         // rows per xg0 block

#define K1 (-1.4426950408889634f)   // -log2(e)   : sigmoid rows (i,f,o)
#define K2 (-2.8853900817779268f)   // -2 log2(e) : tanh rows (g) and tanh(c)

__device__ __forceinline__ float bcastl(float v, int k) {
  return __uint_as_float((unsigned)__builtin_amdgcn_readlane((int)__float_as_uint(v), k));
}
__device__ __forceinline__ float rcpf(float x) { return __builtin_amdgcn_rcpf(x); }
__device__ __forceinline__ float exp2f_(float x) { return __builtin_amdgcn_exp2f(x); }

// quad_perm broadcast: all 4 lanes of each quad get lane (PAT&3)'s value.
template<int PAT>
__device__ __forceinline__ float quadb(float v) {
  return __int_as_float(__builtin_amdgcn_update_dpp(0, __float_as_int(v), PAT, 0xF, 0xF, true));
}

// R14 xg0 (unchanged): LDS-staged tile GEMM, 64 rows/block, uniform
// ds_read_b128 broadcasts, high occupancy so DS/VALU latency is TLP-hidden.
__global__ __launch_bounds__(256) void xg0_gemm_k(
    const float* __restrict__ x, const float* __restrict__ Wih,
    const float* __restrict__ bih, const float* __restrict__ bhh,
    float* __restrict__ xg0)
{
  const int tid = threadIdx.x;
  const int l   = tid & 63;          // output lane (scan layout)
  const int w   = tid >> 6;          // wave id: rows w*16 .. w*16+15
  const int g   = (l & 3) * 16 + (l >> 2);
  const float fac = ((l & 3) == 2) ? K2 : K1;

  __shared__ __align__(16) float xs[XROWS][60];

  float wv[60];
  #pragma unroll
  for (int d = 0; d < 60; ++d) wv[d] = (d < DDIM) ? fac * Wih[g*DDIM + d] : 0.f;
  const float bias = fac * (bih[g] + bhh[g]);

  const int rbase = blockIdx.x * XROWS;
  const float4* xsrc = (const float4*)(x + (size_t)rbase * DDIM); // 64*57*4 % 16 == 0: aligned
  #pragma unroll
  for (int it = 0; it < 4; ++it) {
    int i = tid + it*256;
    if (i < 912) {                     // 912 float4 = 3648 floats = 64 rows
      float4 v = xsrc[i];
      int f0 = 4*i;
      int r0 = f0/57, d0 = f0 - r0*57;            xs[r0][d0] = v.x;
      int f1 = f0+1, r1 = f1/57, d1 = f1 - r1*57; xs[r1][d1] = v.y;
      int f2 = f0+2, r2 = f2/57, d2 = f2 - r2*57; xs[r2][d2] = v.z;
      int f3 = f0+3, r3 = f3/57, d3 = f3 - r3*57; xs[r3][d3] = v.w;
    }
  }
  if (tid < 192) {                     // zero pad cols 57..59 (avoid NaN*0)
    int r = tid/3, c = 57 + (tid - 3*r);
    xs[r][c] = 0.f;
  }
  __syncthreads();

  #pragma unroll
  for (int rr = 0; rr < 16; ++rr) {
    const int r = w*16 + rr;           // wave-uniform -> ds_read broadcast
    const float4* xr = (const float4*)&xs[r][0];
    float a0 = bias, a1 = 0.f, a2 = 0.f, a3 = 0.f;
    #pragma unroll
    for (int i = 0; i < 15; ++i) {
      float4 v = xr[i];
      a0 += wv[4*i]   * v.x;
      a1 += wv[4*i+1] * v.y;
      a2 += wv[4*i+2] * v.z;
      a3 += wv[4*i+3] * v.w;
    }
    xg0[(size_t)(rbase + r)*64 + l] = (a0 + a1) + (a2 + a3);
  }
}

// R14 scan (unchanged, 405.5us proven): 3-wave layer pipeline, epoch
// barriers (G=4 slots/epoch), per-block non-atomic partials.
// R16: cooperative fusion reverted (R15: coop launch costs ~140us in this
// harness vs ~40us/regular boundary; in-kernel epilogue added +44us).
__global__ __launch_bounds__(192, 1) void lstm_scan_pipe_k(
    const float* __restrict__ xg0,
    const int*   __restrict__ lengths,
    const float* __restrict__ Whh0,
    const float* __restrict__ Wih1, const float* __restrict__ Whh1,
    const float* __restrict__ bih1, const float* __restrict__ bhh1,
    const float* __restrict__ Wih2, const float* __restrict__ Whh2,
    const float* __restrict__ bih2, const float* __restrict__ bhh2,
    float* __restrict__ h2buf, float* __restrict__ partial)
{
  const int tid  = threadIdx.x;
  const int wave = tid >> 6;
  const int lane = tid & 63;
  const int gt   = lane & 3;       // 0=i 1=f 2=g 3=o
  const int ch   = lane >> 2;      // channel 0..15
  const int g    = gt*16 + ch;     // weight row (PyTorch i,f,g,o blocks)
  const int b    = blockIdx.x;
  const int len  = lengths[b];
  const bool isg = (gt == 2);
  const float fac = isg ? K2 : K1;
  const float mg = isg ? (2.f*K2) : 1.f;   // g-gate act = K2*tanh (pre-scaled)
  const float ag = isg ? (-K2)    : 0.f;

  __shared__ float lds_h0[NBUF][U][16];
  __shared__ float lds_h1[NBUF][U][16];

  float wa[16], wb[16];
  float bias = 0.f;
  if (wave == 0) {
    #pragma unroll
    for (int k = 0; k < 16; ++k) { wb[k] = fac * Whh0[g*16 + k]; wa[k] = 0.f; }
  } else if (wave == 1) {
    #pragma unroll
    for (int k = 0; k < 16; ++k) { wa[k] = fac * Wih1[g*16 + k]; wb[k] = fac * Whh1[g*16 + k]; }
    bias = fac * (bih1[g] + bhh1[g]);
  } else {
    #pragma unroll
    for (int k = 0; k < 16; ++k) { wa[k] = fac * Wih2[g*16 + k]; wb[k] = fac * Whh2[g*16 + k]; }
    bias = fac * (bih2[g] + bhh2[g]);
  }

  float hs = 0.f, csK = 0.f;            // csK = K2 * c  (pre-scaled recurrence)
  float sum = 0.f, sq = 0.f;
  const int base = b*TT*64 + lane;
  float* __restrict__ h2row = h2buf + (size_t)b*TT*16;

  auto lstm_update = [&](float dot) {
    float s   = rcpf(1.f + exp2f_(dot));
    float act = fmaf(s, mg, ag);          // sigmoid, or K2*tanh for g-gate
    float gi = quadb<0x00>(act);
    float gf = quadb<0x55>(act);
    float gg = quadb<0xAA>(act);          // = K2*tanh(g)
    float go = quadb<0xFF>(act);
    float go2 = go + go;                  // off critical path
    csK = fmaf(gf, csK, gg * gi);         // K2*(f*c + i*g)
    float r = rcpf(1.f + exp2f_(csK));
    hs = fmaf(go2, r, -go);               // go * tanh(c)
  };
  auto owndot = [&](float seed) {         // seed + Whh' . h_own
    float hb[16];                         // ALL broadcasts first (R8 lesson)
    #pragma unroll
    for (int k = 0; k < 16; ++k) hb[k] = bcastl(hs, 4*k);
    float a0 = seed, a1 = 0.f, a2 = 0.f, a3 = 0.f;
    #pragma unroll
    for (int k = 0; k < 16; k += 4) {
      a0 += wb[k]   * hb[k];
      a1 += wb[k+1] * hb[k+1];
      a2 += wb[k+2] * hb[k+2];
      a3 += wb[k+3] * hb[k+3];
    }
    return (a0 + a1) + (a2 + a3);
  };
  auto indot = [&](const float* hin) {    // bias + Wih' . hin (register vector)
    float a0 = bias, a1 = 0.f, a2 = 0.f, a3 = 0.f;
    #pragma unroll
    for (int k = 0; k < 16; k += 4) {
      a0 += wa[k]   * hin[k];
      a1 += wa[k+1] * hin[k+1];
      a2 += wa[k+2] * hin[k+2];
      a3 += wa[k+3] * hin[k+3];
    }
    return (a0 + a1) + (a2 + a3);
  };

  const int NS = (len + U - 1) / U;
  const int E  = (NS + 2*G - 1) / G + 1;

  float cur[U], nxt[U];
  if (wave == 0) {
    #pragma unroll
    for (int j = 0; j < U; ++j) cur[j] = xg0[base + j*64];
    #pragma unroll
    for (int j = 0; j < U; ++j) {
      int ip = U + j; ip = ip > TT-1 ? TT-1 : ip;
      nxt[j] = xg0[base + ip*64];
    }
  }

  for (int e = 0; e < E; ++e) {
    #pragma unroll 1
    for (int q = 0; q < G; ++q) {
      const int tw = G*e + q;
      if (wave == 0) {
        const int t = tw;
        if (t < NS) {
          const int p = t & (NBUF-1);
          float ld[U];
          #pragma unroll
          for (int j = 0; j < U; ++j) {
            int ip = (t + 2)*U + j; ip = ip > TT-1 ? TT-1 : ip;
            ld[j] = xg0[base + ip*64];
          }
          #pragma unroll
          for (int j = 0; j < U; ++j) {
            lstm_update(owndot(cur[j]));
            if (gt == 0) lds_h0[p][j][ch] = hs;
          }
          #pragma unroll
          for (int j = 0; j < U; ++j) { cur[j] = nxt[j]; nxt[j] = ld[j]; }
        }
      } else if (wave == 1) {
        const int t = tw - G;
        if (t >= 0 && t < NS) {
          const int p = t & (NBUF-1);
          float xin[U];
          #pragma unroll
          for (int j = 0; j < U; ++j) {   // ALL input-dots up front, off-chain
            const float4* hp = (const float4*)&lds_h0[p][j][0];
            float4 h0v = hp[0], h1v = hp[1], h2v = hp[2], h3v = hp[3];
            float hin[16] = {h0v.x,h0v.y,h0v.z,h0v.w, h1v.x,h1v.y,h1v.z,h1v.w,
                             h2v.x,h2v.y,h2v.z,h2v.w, h3v.x,h3v.y,h3v.z,h3v.w};
            xin[j] = indot(hin);
          }
          #pragma unroll
          for (int j = 0; j < U; ++j) {
            lstm_update(owndot(xin[j]));
            if (gt == 0) lds_h1[p][j][ch] = hs;
          }
        }
      } else {
        const int t = tw - 2*G;
        if (t >= 0 && t < NS) {
          const int p = t & (NBUF-1);
          float xin[U];
          #pragma unroll
          for (int j = 0; j < U; ++j) {
            const float4* hp = (const float4*)&lds_h1[p][j][0];
            float4 h0v = hp[0], h1v = hp[1], h2v = hp[2], h3v = hp[3];
            float hin[16] = {h0v.x,h0v.y,h0v.z,h0v.w, h1v.x,h1v.y,h1v.z,h1v.w,
                             h2v.x,h2v.y,h2v.z,h2v.w, h3v.x,h3v.y,h3v.z,h3v.w};
            xin[j] = indot(hin);
          }
          #pragma unroll
          for (int j = 0; j < U; ++j) {
            lstm_update(owndot(xin[j]));
            const int ts = t*U + j;
            if (ts < len) {
              if (gt == 0) h2row[ts*16 + ch] = hs;
              sum += hs; sq += hs*hs;
            }
          }
        }
      }
    }
    __syncthreads();
  }

  for (int idx = len*16 + tid; idx < TT*16; idx += 192)
    h2row[idx] = 0.f;

  if (wave == 2 && gt == 0) {            // non-atomic per-block partials
    partial[b*32 + ch]      = sum;
    partial[b*32 + 16 + ch] = sq;
  }
}

// R16 finalize: prep folded in. Every block redundantly reduces the 8192
// partials (32KB, L2-broadcast-friendly) -> BN+FC coef in LDS -> transforms
// its 256 h2 rows. Drops the separate prep_k launch (~40us boundary).
__global__ __launch_bounds__(256) void finalize_k(
    const float* __restrict__ partial,
    const float* __restrict__ gamma, const float* __restrict__ beta,
    const float* __restrict__ fcw, const float* __restrict__ fcb,
    const float* __restrict__ h2buf, float* __restrict__ out)
{
  const int tid = threadIdx.x;
  __shared__ float red[8][32];
  __shared__ float coef_s[68];

  const int c = tid & 31, chunk = tid >> 5;   // 8 chunks x 32 channels
  float acc = 0.f;
  #pragma unroll 4
  for (int bb = chunk; bb < BBATCH; bb += 8)
    acc += partial[bb*32 + c];
  red[chunk][c] = acc;
  __syncthreads();
  if (tid < 32) {
    float tot = 0.f;
    #pragma unroll
    for (int k = 0; k < 8; ++k) tot += red[k][tid];
    red[0][tid] = tot;
  }
  __syncthreads();
  if (tid < 64) {
    const int o = tid >> 4, c2 = tid & 15;
    const float inv_n = 1.0f / NF;
    float mean = red[0][c2] * inv_n;
    float var  = red[0][16 + c2] * inv_n - mean*mean;
    float s  = gamma[c2] * rsqrtf(var + 1e-5f);
    float tb = beta[c2] - mean * s;
    float woc = fcw[o*16 + c2];
    coef_s[tid] = s * woc;
    float term = tb * woc;
    #pragma unroll
    for (int off = 1; off < 16; off <<= 1) term += __shfl_xor(term, off, 16);
    if (c2 == 0) coef_s[64 + o] = fcb[o] + term;
  }
  __syncthreads();

  const int r = blockIdx.x * 256 + tid;
  const float4* hp = (const float4*)(h2buf + (size_t)r * 16);
  float4 v0 = hp[0], v1 = hp[1], v2 = hp[2], v3 = hp[3];
  float hv[16] = {v0.x,v0.y,v0.z,v0.w, v1.x,v1.y,v1.z,v1.w,
                  v2.x,v2.y,v2.z,v2.w, v3.x,v3.y,v3.z,v3.w};
  float4 o4;
  float* op = &o4.x;
  #pragma unroll
  for (int o = 0; o < 4; ++o) {
    float a = coef_s[64 + o];
    #pragma unroll
    for (int c3 = 0; c3 < 16; ++c3) a += coef_s[o*16 + c3] * hv[c3];
    op[o] = a;
  }
  ((float4*)out)[r] = o4;
}

extern "C" void kernel_launch(void* const* d_in, const int* in_sizes, int n_in,
                              void* d_out, int out_size, void* d_ws, size_t ws_size,
                              hipStream_t stream)
{
  const float* x     = (const float*)d_in[0];
  const int* lengths = (const int*)d_in[1];
  const float* W_ih0 = (const float*)d_in[2];
  const float* W_hh0 = (const float*)d_in[3];
  const float* b_ih0 = (const float*)d_in[4];
  const float* b_hh0 = (const float*)d_in[5];
  const float* W_ih1 = (const float*)d_in[6];
  const float* W_hh1 = (const float*)d_in[7];
  const float* b_ih1 = (const float*)d_in[8];
  const float* b_hh1 = (const float*)d_in[9];
  const float* W_ih2 = (const float*)d_in[10];
  const float* W_hh2 = (const float*)d_in[11];
  const float* b_ih2 = (const float*)d_in[12];
  const float* b_hh2 = (const float*)d_in[13];
  const float* gamma = (const float*)d_in[14];
  const float* beta  = (const float*)d_in[15];
  const float* fcw   = (const float*)d_in[16];
  const float* fcb   = (const float*)d_in[17];
  float* out = (float*)d_out;

  float* ws      = (float*)d_ws;
  float* xg0     = ws;                        // B*T*64 floats (128 MB)
  float* h2      = ws + 33554432;             // B*T*16 floats (32 MB)
  float* partial = ws + 33554432 + 8388608;   // 256*32 floats

  hipLaunchKernelGGL(xg0_gemm_k, dim3(NROWS/XROWS), dim3(256), 0, stream,
                     x, W_ih0, b_ih0, b_hh0, xg0);
  hipLaunchKernelGGL(lstm_scan_pipe_k, dim3(256), dim3(192), 0, stream,
                     xg0, lengths, W_hh0, W_ih1, W_hh1, b_ih1, b_hh1,
                     W_ih2, W_hh2, b_ih2, b_hh2, h2, partial);
  hipLaunchKernelGGL(finalize_k, dim3(2048), dim3(256), 0, stream,
                     partial, gamma, beta, fcw, fcb, h2, out);
}